// Round 4
// baseline (356.431 us; speedup 1.0000x reference)
//
#include <hip/hip_runtime.h>

namespace {
constexpr int NWIN = 512;
constexpr int M    = 32;
constexpr int H    = 8;
constexpr int C    = 16;
constexpr int NSIG = 3;
constexpr int HC   = H * C;  // 128 floats per voxel row
}

__device__ __forceinline__ float dot4(const float4& a, const float4& b) {
  return a.x * b.x + a.y * b.y + a.z * b.z + a.w * b.w;
}
__device__ __forceinline__ const float4* f4p(const float* p) {
  return reinterpret_cast<const float4*>(p);
}

// One block per window. Thread t -> (h = t>>5, i = t&31): owns output row
// (window w, voxel i, head h), computes all 32 logits + softmax + PV in regs.
__global__ __launch_bounds__(256, 2)
void win_attn(const float* __restrict__ qf, const float* __restrict__ kf,
              const float* __restrict__ vf, const float* __restrict__ qt,
              const float* __restrict__ kt, const float* __restrict__ vt,
              const int* __restrict__ toff, const int* __restrict__ widx,
              const int* __restrict__ tidx, float* __restrict__ out)
{
  const int w = blockIdx.x;
  const int t = threadIdx.x;
  const int h = t >> 5;
  const int i = t & 31;

  // k/v natural layout: phase-1/PV reads are same-address broadcasts across
  // the 32 i-lanes -> no bank conflicts. table_idx transposed so per-(j,s)
  // reads land on bank = i -> conflict-free.
  __shared__ float k_lds[M][HC];            // 16 KB
  __shared__ float v_lds[M][HC];            // 16 KB
  __shared__ int   tid_lds[M * NSIG * M];   // 12 KB, [(j*3+s)*32 + i]
  __shared__ int   vox_lds[M];
  __shared__ int   off_lds[NSIG];

  if (t < M)    vox_lds[t] = widx[w * M + t];
  if (t < NSIG) off_lds[t] = toff[t];
  __syncthreads();

  // Stage k, v: coalesced 512B-per-32-lanes global reads.
  #pragma unroll
  for (int r = 0; r < 4; ++r) {
    const int flat = t + 256 * r;        // [0,1024)
    const int j    = flat >> 5;
    const int f4i  = (flat & 31) * 4;
    const int vox  = vox_lds[j];
    *reinterpret_cast<float4*>(&k_lds[j][f4i]) = *f4p(kf + vox * HC + f4i);
    *reinterpret_cast<float4*>(&v_lds[j][f4i]) = *f4p(vf + vox * HC + f4i);
  }
  // Stage table_idx (global layout [i][j][s]) transposed to [(j*3+s)*32+i].
  #pragma unroll
  for (int r = 0; r < 12; ++r) {
    const int g   = t + 256 * r;         // [0,3072)
    const int ii  = g / 96;
    const int rem = g - ii * 96;
    const int jj  = rem / 3;
    const int ss  = rem - jj * 3;
    tid_lds[(jj * NSIG + ss) * M + ii] = tidx[w * (M * M * NSIG) + g];
  }

  // q row for (i,h) into registers (16 floats).
  const int vox_i = vox_lds[i];
  const float* qrow = qf + vox_i * HC + h * C;
  const float4 q0 = *f4p(qrow + 0),  q1 = *f4p(qrow + 4),
               q2 = *f4p(qrow + 8),  q3 = *f4p(qrow + 12);
  const int offs[NSIG] = { off_lds[0], off_lds[1], off_lds[2] };
  __syncthreads();

  // ---- Phase 1: logits (fully unrolled j so lg[] stays in registers) ----
  float lg[M];
  #pragma unroll
  for (int j = 0; j < M; ++j) {
    const float* krow = &k_lds[j][h * C];
    const float4 k0 = *f4p(krow + 0),  k1 = *f4p(krow + 4),
                 k2 = *f4p(krow + 8),  k3 = *f4p(krow + 12);
    float acc = dot4(q0, k0) + dot4(q1, k1) + dot4(q2, k2) + dot4(q3, k3);
    #pragma unroll
    for (int s = 0; s < NSIG; ++s) {
      const int row = offs[s] + tid_lds[(j * NSIG + s) * M + i];
      const float* tqr = qt + row * HC + h * C;
      const float4 a0 = *f4p(tqr + 0),  a1 = *f4p(tqr + 4),
                   a2 = *f4p(tqr + 8),  a3 = *f4p(tqr + 12);
      acc += dot4(q0, a0) + dot4(q1, a1) + dot4(q2, a2) + dot4(q3, a3);
      const float* tkr = kt + row * HC + h * C;
      const float4 b0 = *f4p(tkr + 0),  b1 = *f4p(tkr + 4),
                   b2 = *f4p(tkr + 8),  b3 = *f4p(tkr + 12);
      acc += dot4(k0, b0) + dot4(k1, b1) + dot4(k2, b2) + dot4(k3, b3);
    }
    lg[j] = acc;
  }

  // ---- Phase 2: max-stabilized softmax, all in registers ----
  float m = lg[0];
  #pragma unroll
  for (int j = 1; j < M; ++j) m = fmaxf(m, lg[j]);
  float ssum = 0.f;
  #pragma unroll
  for (int j = 0; j < M; ++j) { lg[j] = expf(lg[j] - m); ssum += lg[j]; }

  // ---- Phase 3: PV + table-V ----
  float oacc[C];
  #pragma unroll
  for (int c = 0; c < C; ++c) oacc[c] = 0.f;
  #pragma unroll
  for (int j = 0; j < M; ++j) {
    const float e = lg[j];
    const float* vrow = &v_lds[j][h * C];
    #pragma unroll
    for (int c4 = 0; c4 < 4; ++c4) {
      const float4 vv = *f4p(vrow + 4 * c4);
      oacc[4 * c4 + 0] += e * vv.x;
      oacc[4 * c4 + 1] += e * vv.y;
      oacc[4 * c4 + 2] += e * vv.z;
      oacc[4 * c4 + 3] += e * vv.w;
    }
    #pragma unroll
    for (int s = 0; s < NSIG; ++s) {
      const int row = offs[s] + tid_lds[(j * NSIG + s) * M + i];
      const float* tvr = vt + row * HC + h * C;
      #pragma unroll
      for (int c4 = 0; c4 < 4; ++c4) {
        const float4 tv = *f4p(tvr + 4 * c4);
        oacc[4 * c4 + 0] += e * tv.x;
        oacc[4 * c4 + 1] += e * tv.y;
        oacc[4 * c4 + 2] += e * tv.z;
        oacc[4 * c4 + 3] += e * tv.w;
      }
    }
  }

  const float inv = 1.0f / ssum;
  float* orow = out + vox_i * HC + h * C;
  #pragma unroll
  for (int c4 = 0; c4 < 4; ++c4) {
    float4 o;
    o.x = oacc[4 * c4 + 0] * inv;
    o.y = oacc[4 * c4 + 1] * inv;
    o.z = oacc[4 * c4 + 2] * inv;
    o.w = oacc[4 * c4 + 3] * inv;
    *reinterpret_cast<float4*>(orow + 4 * c4) = o;
  }
}

extern "C" void kernel_launch(void* const* d_in, const int* in_sizes, int n_in,
                              void* d_out, int out_size, void* d_ws, size_t ws_size,
                              hipStream_t stream) {
  (void)in_sizes; (void)n_in; (void)d_ws; (void)ws_size; (void)out_size;
  const float* qf  = (const float*)d_in[0];
  const float* kf  = (const float*)d_in[1];
  const float* vf  = (const float*)d_in[2];
  const float* qt  = (const float*)d_in[3];
  const float* kt  = (const float*)d_in[4];
  const float* vt  = (const float*)d_in[5];
  const int*  toff = (const int*)d_in[6];
  const int*  widx = (const int*)d_in[7];
  const int*  tidx = (const int*)d_in[8];
  float* out = (float*)d_out;
  win_attn<<<NWIN, 256, 0, stream>>>(qf, kf, vf, qt, kt, vt, toff, widx, tidx, out);
}